// Round 12
// baseline (1814.907 us; speedup 1.0000x reference)
//
#include <hip/hip_runtime.h>

// HNM discriminative loss, MI355X — R15.
// predict (4,32,512,1024) f32, target (4,512,1024) i32 -> scalar f32.
// R15: R14 proved k_var invariant (~155us) across FOUR structures -> the
// memory-system service rate for its pattern is the cap, and neither kernel
// has shown a counter row since R6 (both hide under the 159us ws-poison
// fill). Fuse accum+var into ONE ~270us dispatch = visible counters.
// Residency-safe by construction (R13's fusion failed at 2 blk/CU):
// launch_bounds(256,8) caps VGPR<=64; LDS 19776B <= 20480B/block ->
// EXACTLY 8 blk/CU x 256 CU = 2048-block grid fully resident, barrier safe.
// Phase A = R11's proven accum at its proven occupancy; counts distributed
// 1024px/block (no stragglers). Phase B = px-quad channel loop, centers in
// 16 distributed VGPRs via ds_bpermute, per-wave lane-column LDS hist
// (reuses phase A array; 2 rounds sq/pos). Mid = distributed 627-job reduce
// (job map verified against grid=2048: all jobs < 627 < 2048).

#define K_CLS 19
#define C_CH 32
#define HW_SHIFT 19            // H*W = 512*1024 = 2^19
#define EPSF 1e-12f
#define THEA_F 0.5f
#define TWO_DELTA 3.0f
#define MIN_PIX 20.0f
#define NBLK 2048

// ---- ws float layout ------------------------------------------------------
#define OFF_PSUM 0                        // [32 ch][64 slots][20] = 40960
#define OFF_PCNT 40960                    // [2048 blk][20] = 40960
#define OFF_RED  81920                    // 608 sums + 19 counts (pad 640)
#define OFF_VRED 82560                    // 38 reduced sq/pos (pad 64)
#define OFF_VPART 82624                   // [2048 blk][64]
#define OFF_BAR  213696                   // 32 uints: 2 phases x 16 stripes

__device__ __forceinline__ void atomAddF(float* p, float v) {
  unsafeAtomicAdd(p, v);       // k_final only
}

__device__ __forceinline__ float bperm(float v, int byteidx) {
  return __int_as_float(__builtin_amdgcn_ds_bpermute(byteidx, __float_as_int(v)));
}

__device__ __forceinline__ void grid_barrier(unsigned* bar, int phase) {
  __syncthreads();
  if (threadIdx.x == 0) {
    __threadfence();
    __hip_atomic_fetch_add(&bar[phase * 16 + (blockIdx.x & 15)], 1u,
                           __ATOMIC_RELEASE, __HIP_MEMORY_SCOPE_AGENT);
    unsigned sum = 0;
    do {
      __builtin_amdgcn_s_sleep(8);
      sum = 0;
      for (int i = 0; i < 16; ++i)
        sum += __hip_atomic_load(&bar[phase * 16 + i],
                                 __ATOMIC_ACQUIRE, __HIP_MEMORY_SCOPE_AGENT);
    } while (sum < NBLK);
  }
  __syncthreads();
}

// LDS: 4944 floats = 19776 B <= 20480 (160KB/8). hist = [0,4864); s_w = [4864,4944)
__global__ __launch_bounds__(256, 8) void k_fused(
    const float* __restrict__ pred, const int* __restrict__ tgt,
    float* __restrict__ ws, unsigned* __restrict__ bar)
{
  __shared__ float smf[4944];
  const int t = threadIdx.x;
  const int w = t >> 6;
  const int lane = t & 63;
  const int bid = blockIdx.x;
  float* col = smf + w * (K_CLS * 64) + lane;   // thread-private column
  float* s_w = smf + 4864;                      // [4][20]

  // ======== Phase A ========================================================
  {
#pragma unroll
    for (int k = 0; k < K_CLS; ++k) col[k << 6] = 0.f;

    // -- counts: strip of 1024 px at bid*1024 (each pixel counted once) --
    {
      const int4 c4 = *reinterpret_cast<const int4*>(tgt + (size_t)bid * 1024 + t * 4);
      const int s[4] = {c4.x, c4.y, c4.z, c4.w};
#pragma unroll
      for (int i = 0; i < 4; ++i) {
        const int kk = min((unsigned)s[i], 18u);
        col[kk << 6] += ((unsigned)s[i] < K_CLS) ? 1.f : 0.f;
      }
      float acc[K_CLS];
#pragma unroll
      for (int k = 0; k < K_CLS; ++k) acc[k] = col[k << 6];
#pragma unroll
      for (int k = 0; k < K_CLS; ++k) {
        float s2 = acc[k];
#pragma unroll
        for (int m = 1; m < 64; m <<= 1) s2 += __shfl_xor(s2, m, 64);
        acc[k] = s2;
      }
#pragma unroll
      for (int k = 0; k < K_CLS; ++k)
        if (lane == k) s_w[w * 20 + k] = acc[k];
      __syncthreads();
      if (t < K_CLS)
        ws[OFF_PCNT + bid * 20 + t] = s_w[0 * 20 + t] + s_w[1 * 20 + t]
                                    + s_w[2 * 20 + t] + s_w[3 * 20 + t];
      __syncthreads();
#pragma unroll
      for (int k = 0; k < K_CLS; ++k) col[k << 6] = 0.f;
    }

    // -- feature sums: plane = bid>>4, slab = bid&15 (32768 px, contiguous) --
    const int plane = bid >> 4;            // 0..127 = n*32+ch
    const int slab  = bid & 15;
    const int n_idx = plane >> 5;
    const int ch    = plane & 31;
    const float* pbase = pred + (((size_t)plane) << HW_SHIFT) + ((size_t)slab << 15);
    const int*   tbase = tgt  + (((size_t)n_idx) << HW_SHIFT) + ((size_t)slab << 15);

    float4 vA = *reinterpret_cast<const float4*>(pbase + t * 4);
    int4   cA = *reinterpret_cast<const int4*>(tbase + t * 4);
#pragma unroll 1
    for (int it = 0; it < 32; ++it) {
      float4 vB; int4 cB;
      if (it + 1 < 32) {
        vB = *reinterpret_cast<const float4*>(pbase + (it + 1) * 1024 + t * 4);
        cB = *reinterpret_cast<const int4*>(tbase + (it + 1) * 1024 + t * 4);
      }
      const float x[4] = {vA.x, vA.y, vA.z, vA.w};
      const int   s[4] = {cA.x, cA.y, cA.z, cA.w};
      const int   k0 = min((unsigned)s[0], 18u), k1 = min((unsigned)s[1], 18u);
      const int   k2 = min((unsigned)s[2], 18u), k3 = min((unsigned)s[3], 18u);
      const float v0 = ((unsigned)s[0] < K_CLS) ? x[0] : 0.f;
      const float v1 = ((unsigned)s[1] < K_CLS) ? x[1] : 0.f;
      const float v2 = ((unsigned)s[2] < K_CLS) ? x[2] : 0.f;
      const float v3 = ((unsigned)s[3] < K_CLS) ? x[3] : 0.f;
      col[k0 << 6] += v0;
      col[k1 << 6] += v1;
      col[k2 << 6] += v2;
      col[k3 << 6] += v3;
      vA = vB; cA = cB;
    }

    float acc[K_CLS];
#pragma unroll
    for (int k = 0; k < K_CLS; ++k) acc[k] = col[k << 6];
#pragma unroll
    for (int k = 0; k < K_CLS; ++k) {
      float s2 = acc[k];
#pragma unroll
      for (int m = 1; m < 64; m <<= 1) s2 += __shfl_xor(s2, m, 64);
      acc[k] = s2;
    }
#pragma unroll
    for (int k = 0; k < K_CLS; ++k)
      if (lane == k) s_w[w * 20 + k] = acc[k];
    __syncthreads();
    if (t < K_CLS) {
      const int slot = n_idx * 16 + slab;    // 0..63
      ws[OFF_PSUM + ch * 1280 + slot * 20 + t] =
          s_w[0 * 20 + t] + s_w[1 * 20 + t] + s_w[2 * 20 + t] + s_w[3 * 20 + t];
    }
  }

  // ======== Mid: barrier, distributed 627-job reduce ======================
  grid_barrier(bar, 0);

  if (bid < 608) {
    const int ch = bid / K_CLS, k = bid - ch * K_CLS;
    if (t < 64) {
      float a = ws[OFF_PSUM + ch * 1280 + lane * 20 + k];   // lane = slot
#pragma unroll
      for (int m = 1; m < 64; m <<= 1) a += __shfl_xor(a, m, 64);
      if (lane == 0) ws[OFF_RED + bid] = a;
    }
  } else if (bid < 627) {
    const int k = bid - 608;
    float a = 0.f;
#pragma unroll
    for (int r = 0; r < 8; ++r)
      a += ws[OFF_PCNT + (size_t)(t + r * 256) * 20 + k];
#pragma unroll
    for (int m = 1; m < 64; m <<= 1) a += __shfl_xor(a, m, 64);
    if (lane == 0) s_w[w] = a;
    __syncthreads();
    if (t == 0) ws[OFF_RED + 608 + k] = s_w[0] + s_w[1] + s_w[2] + s_w[3];
  }

  grid_barrier(bar, 1);

  // ======== Phase B: variance (1024 px/block) =============================
  {
    // distributed centers: lane holds (c = 2r + (lane>>5), k = lane&31)
    const int kk = lane & 31;
    const float invc = (kk < K_CLS) ? 1.f / fmaxf(ws[OFF_RED + 608 + kk], 1.f) : 0.f;
    float ctrd[16];
#pragma unroll
    for (int r = 0; r < 16; ++r) {
      const int c = 2 * r + (lane >> 5);
      ctrd[r] = (kk < K_CLS) ? ws[OFF_RED + c * K_CLS + kk] * invc : 0.f;
    }

#pragma unroll
    for (int k = 0; k < K_CLS; ++k) col[k << 6] = 0.f;   // sq hist round

    const int n_idx = bid >> 9;                     // 512 blocks per image
    const int hw = ((bid & 511) << 10) + t * 4;
    const float* pb = pred + (((size_t)(n_idx * C_CH)) << HW_SHIFT) + hw;

    const int4 c4 = *reinterpret_cast<const int4*>(
        tgt + (((size_t)n_idx) << HW_SHIFT) + hw);
    const int cls[4] = {c4.x, c4.y, c4.z, c4.w};
    bool vl[4]; int sc[4]; int idx4[4];
#pragma unroll
    for (int j = 0; j < 4; ++j) {
      vl[j] = (unsigned)cls[j] < K_CLS;
      sc[j] = vl[j] ? cls[j] : 0;
      idx4[j] = sc[j] << 2;
    }

    float d2[4] = {0.f, 0.f, 0.f, 0.f};
#pragma unroll
    for (int c = 0; c < C_CH; ++c) {
      const float4 x = *reinterpret_cast<const float4*>(pb + ((size_t)c << HW_SHIFT));
      const int hi = (c & 1) << 7;                 // src-lane offset *4
      const float cv0 = bperm(ctrd[c >> 1], idx4[0] + hi);
      const float cv1 = bperm(ctrd[c >> 1], idx4[1] + hi);
      const float cv2 = bperm(ctrd[c >> 1], idx4[2] + hi);
      const float cv3 = bperm(ctrd[c >> 1], idx4[3] + hi);
      const float e0 = cv0 - x.x, e1 = cv1 - x.y, e2 = cv2 - x.z, e3 = cv3 - x.w;
      d2[0] = fmaf(e0, e0, d2[0]);
      d2[1] = fmaf(e1, e1, d2[1]);
      d2[2] = fmaf(e2, e2, d2[2]);
      d2[3] = fmaf(e3, e3, d2[3]);
    }

    bool act[4]; float rr[4];
#pragma unroll
    for (int j = 0; j < 4; ++j) {
      const float r = sqrtf(d2[j] + EPSF) - THEA_F;
      act[j] = vl[j] && (r > 0.f);
      rr[j] = act[j] ? r * r : 0.f;
      col[sc[j] << 6] += rr[j];                    // adds 0 if !act
    }

    // flush sq
    {
      float acc[K_CLS];
#pragma unroll
      for (int k = 0; k < K_CLS; ++k) acc[k] = col[k << 6];
#pragma unroll
      for (int k = 0; k < K_CLS; ++k) {
        float s2 = acc[k];
#pragma unroll
        for (int m = 1; m < 64; m <<= 1) s2 += __shfl_xor(s2, m, 64);
        acc[k] = s2;
      }
#pragma unroll
      for (int k = 0; k < K_CLS; ++k)
        if (lane == k) s_w[w * 20 + k] = acc[k];
      __syncthreads();
      if (t < K_CLS)
        ws[OFF_VPART + (size_t)bid * 64 + t] =
            s_w[0 * 20 + t] + s_w[1 * 20 + t] + s_w[2 * 20 + t] + s_w[3 * 20 + t];
      __syncthreads();                             // s_w safe to rewrite
    }

    // pos round
#pragma unroll
    for (int k = 0; k < K_CLS; ++k) col[k << 6] = 0.f;
#pragma unroll
    for (int j = 0; j < 4; ++j)
      col[sc[j] << 6] += act[j] ? 1.f : 0.f;
    {
      float acc[K_CLS];
#pragma unroll
      for (int k = 0; k < K_CLS; ++k) acc[k] = col[k << 6];
#pragma unroll
      for (int k = 0; k < K_CLS; ++k) {
        float s2 = acc[k];
#pragma unroll
        for (int m = 1; m < 64; m <<= 1) s2 += __shfl_xor(s2, m, 64);
        acc[k] = s2;
      }
#pragma unroll
      for (int k = 0; k < K_CLS; ++k)
        if (lane == k) s_w[w * 20 + k] = acc[k];
      __syncthreads();
      if (t < K_CLS)
        ws[OFF_VPART + (size_t)bid * 64 + K_CLS + t] =
            s_w[0 * 20 + t] + s_w[1 * 20 + t] + s_w[2 * 20 + t] + s_w[3 * 20 + t];
    }
  }
}

// ---- Pre-reduce sq/pos: 38 blocks over 2048 partials ----------------------
__global__ __launch_bounds__(256) void k_vred(float* __restrict__ ws)
{
  const int o = blockIdx.x;            // 0..37 (sq 0..18, pos 19..37)
  const int t = threadIdx.x;
  float a = 0.f;
#pragma unroll
  for (int r = 0; r < 8; ++r)
    a += ws[OFF_VPART + (size_t)(t + r * 256) * 64 + o];
#pragma unroll
  for (int m = 1; m < 64; m <<= 1) a += __shfl_xor(a, m, 64);
  __shared__ float s[4];
  if ((t & 63) == 0) s[t >> 6] = a;
  __syncthreads();
  if (t == 0) ws[OFF_VRED + o] = s[0] + s[1] + s[2] + s[3];
}

// ---- Finalize -------------------------------------------------------------
__global__ __launch_bounds__(1024) void k_final(
    float* __restrict__ ws, float* __restrict__ out)
{
  __shared__ float s_ctr[C_CH * K_CLS];
  __shared__ float s_valid[K_CLS];
  __shared__ float s_red[3];
  __shared__ float s_ncls;
  const int t = threadIdx.x;
  if (t < 3) s_red[t] = 0.f;
  if (t < K_CLS) s_valid[t] = (ws[OFF_RED + C_CH * K_CLS + t] > MIN_PIX) ? 1.f : 0.f;
  for (int i = t; i < C_CH * K_CLS; i += 1024) {
    const int k = i % K_CLS;
    s_ctr[i] = ws[OFF_RED + i] / fmaxf(ws[OFF_RED + C_CH * K_CLS + k], 1.f);
  }
  __syncthreads();

  if (t == 0) {
    float n = 0.f;
    for (int k = 0; k < K_CLS; ++k) n += s_valid[k];
    s_ncls = fmaxf(n, 1.f);
  }
  if (t < K_CLS && s_valid[t] > 0.f) {
    const float sq  = ws[OFF_VRED + t];
    const float pos = ws[OFF_VRED + K_CLS + t];
    atomAddF(&s_red[0], sq / fmaxf(pos, 1.f));
    float nn = 0.f;
#pragma unroll
    for (int ch = 0; ch < C_CH; ++ch) {
      const float cv = s_ctr[ch * K_CLS + t];
      nn = fmaf(cv, cv, nn);
    }
    atomAddF(&s_red[2], sqrtf(nn + EPSF));
  }
  if (t < K_CLS * K_CLS) {
    const int a = t / K_CLS, b = t - (t / K_CLS) * K_CLS;
    if (a != b && s_valid[a] > 0.f && s_valid[b] > 0.f) {
      float dd = 0.f;
#pragma unroll
      for (int ch = 0; ch < C_CH; ++ch) {
        const float df = s_ctr[ch * K_CLS + a] - s_ctr[ch * K_CLS + b];
        dd = fmaf(df, df, dd);
      }
      const float dist = sqrtf(dd + EPSF);
      const float d = fmaxf(TWO_DELTA - dist, 0.f);
      if (d > 0.f) atomAddF(&s_red[1], d * d);
    }
  }
  __syncthreads();
  if (t == 0) {
    const float n = s_ncls;
    out[0] = s_red[0] / n
           + s_red[1] / fmaxf(n * (n - 1.f), 1.f)
           + 0.001f * s_red[2] / n;
  }
}

extern "C" void kernel_launch(void* const* d_in, const int* in_sizes, int n_in,
                              void* d_out, int out_size, void* d_ws, size_t ws_size,
                              hipStream_t stream) {
  const float* pred = (const float*)d_in[0];
  const int*   tgt  = (const int*)d_in[1];
  float* ws  = (float*)d_ws;
  float* out = (float*)d_out;

  hipMemsetAsync((char*)d_ws + (size_t)OFF_BAR * 4, 0, 32 * 4, stream);
  k_fused<<<NBLK, 256, 0, stream>>>(pred, tgt, ws,
                                    (unsigned*)((float*)d_ws + OFF_BAR));
  k_vred <<<2 * K_CLS, 256, 0, stream>>>(ws);
  k_final<<<1, 1024, 0, stream>>>(ws, out);
}

// Round 13
// 443.866 us; speedup vs baseline: 4.0889x; 4.0889x over previous
//
#include <hip/hip_runtime.h>

// HNM discriminative loss, MI355X — R16.
// predict (4,32,512,1024) f32, target (4,512,1024) i32 -> scalar f32.
// R16: R15's counters (VGPR=32 + WRITE_SIZE 9.1MB scratch vs 227KB) = spill
// from launch_bounds(,8). RULE: never force min-waves; spills cost more than
// occupancy buys. Fusion abandoned (0-for-2). Surviving theory from the
// session's own contrast: accum's CONTIGUOUS 128KB/block pred reads serve
// 4.3 TB/s; every var's 32x strided-4KB-chunk reads serve 1.7 TB/s across
// FOUR structures -> pattern service rate is the cap. Fix: channel-OUTER
// var via the algebraic split (d2 = sum_c x^2 - 2 sum_c x*ctr + |ctr|^2
// decomposes per channel): block owns 2048px, reads one contiguous 8KB
// chunk per channel; nrm/dot in regs; ds_bpermute ctr gather (full-wave,
// proven R14/R15). Secondary: u8 class-map prepass (2MB) cuts accum's tgt
// re-reads 256MB -> 64MB. No launch_bounds caps anywhere.

#define K_CLS 19
#define C_CH 32
#define HW_SHIFT 19            // H*W = 512*1024 = 2^19
#define HW_SIZE (1 << HW_SHIFT)
#define EPSF 1e-12f
#define THEA_F 0.5f
#define TWO_DELTA 3.0f
#define MIN_PIX 20.0f

// ---- ws float layout ------------------------------------------------------
#define OFF_PSUM 0                       // [ch][64 slots][20] = 40960
#define OFF_PCNT 40960                   // [64 slots][20] = 1280
#define OFF_RED  42240                   // 608 sums + 19 counts (pad 640)
#define OFF_VRED 42880                   // 38 reduced sq/pos (pad 64)
#define OFF_VPART 42944                  // [1024 blk][64]: 19 sq + 19 pos
#define OFF_MAP  108480                  // u8 class map: 2MB = 524288 floats
#define WS_FLOATS (OFF_MAP + 524288)

__device__ __forceinline__ void atomAddF(float* p, float v) {
  unsafeAtomicAdd(p, v);       // cold paths only
}

__device__ __forceinline__ float bperm(float v, int byteidx) {
  return __int_as_float(__builtin_amdgcn_ds_bpermute(byteidx, __float_as_int(v)));
}

// ---- Pack: tgt int32 -> u8 class map (2MB). ~3us. -------------------------
__global__ __launch_bounds__(256) void k_pack(
    const int* __restrict__ tgt, float* __restrict__ ws)
{
  const int i = blockIdx.x * 256 + threadIdx.x;   // word index, 4 px each
  const int4 c = *reinterpret_cast<const int4*>(tgt + (size_t)i * 4);
  const unsigned u = (unsigned)(c.x & 255) | ((unsigned)(c.y & 255) << 8)
                   | ((unsigned)(c.z & 255) << 16) | ((unsigned)(c.w & 255) << 24);
  reinterpret_cast<unsigned*>(ws + OFF_MAP)[i] = u;
}

// ---- Pass 1: single-parity bank-per-lane histogram, u8 map reads ----------
__global__ __launch_bounds__(256) void k_accum(
    const float* __restrict__ pred, float* __restrict__ ws)
{
  __shared__ float sA[4][K_CLS][64];            // 19456 B -> 8 blocks/CU
  __shared__ float s_w[4][20];
  const int t = threadIdx.x;
  const int w = t >> 6;
  const int lane = t & 63;
  const unsigned* umap = reinterpret_cast<const unsigned*>(ws + OFF_MAP);
  float* colA = &sA[w][0][lane];                // colA[k<<6] = bin k, bank l%32
#pragma unroll
  for (int k = 0; k < K_CLS; ++k) colA[k << 6] = 0.f;

  if (blockIdx.x < 2048) {
    const int plane = blockIdx.x >> 4;       // 0..127
    const int slab  = blockIdx.x & 15;       // 0..15
    const int n_idx = plane >> 5;
    const int ch    = plane & 31;
    const float* pbase = pred + (((size_t)plane) << HW_SHIFT) + ((size_t)slab << 15);
    const int mbase = ((n_idx << HW_SHIFT) + (slab << 15)) >> 2;

    float4 vA = *reinterpret_cast<const float4*>(pbase + t * 4);
    unsigned mA = umap[mbase + t];
#pragma unroll 1
    for (int it = 0; it < 32; ++it) {
      float4 vB; unsigned mB;
      if (it + 1 < 32) {
        vB = *reinterpret_cast<const float4*>(pbase + (it + 1) * 1024 + t * 4);
        mB = umap[mbase + (it + 1) * 256 + t];
      }
      const unsigned b0 = mA & 255u, b1 = (mA >> 8) & 255u;
      const unsigned b2 = (mA >> 16) & 255u, b3 = mA >> 24;
      const int   k0 = min(b0, 18u), k1 = min(b1, 18u);
      const int   k2 = min(b2, 18u), k3 = min(b3, 18u);
      const float v0 = (b0 < K_CLS) ? vA.x : 0.f;
      const float v1 = (b1 < K_CLS) ? vA.y : 0.f;
      const float v2 = (b2 < K_CLS) ? vA.z : 0.f;
      const float v3 = (b3 < K_CLS) ? vA.w : 0.f;
      colA[k0 << 6] += v0;
      colA[k1 << 6] += v1;
      colA[k2 << 6] += v2;
      colA[k3 << 6] += v3;
      vA = vB; mA = mB;
    }

    float acc[K_CLS];
#pragma unroll
    for (int k = 0; k < K_CLS; ++k) acc[k] = colA[k << 6];
#pragma unroll
    for (int k = 0; k < K_CLS; ++k) {
      float s = acc[k];
#pragma unroll
      for (int m = 1; m < 64; m <<= 1) s += __shfl_xor(s, m, 64);
      acc[k] = s;
    }
#pragma unroll
    for (int k = 0; k < K_CLS; ++k)
      if (lane == k) s_w[w][k] = acc[k];
    __syncthreads();
    if (t < K_CLS) {
      const int slot = n_idx * 16 + slab;
      ws[OFF_PSUM + ch * (64 * 20) + slot * 20 + t] =
          s_w[0][t] + s_w[1][t] + s_w[2][t] + s_w[3][t];
    }
  } else {
    const int idx = blockIdx.x - 2048;       // 0..63
    const int mbase = idx << 13;             // (idx*32768)/4

#pragma unroll 1
    for (int it = 0; it < 32; ++it) {
      const unsigned m = umap[mbase + it * 256 + t];
      const unsigned b0 = m & 255u, b1 = (m >> 8) & 255u;
      const unsigned b2 = (m >> 16) & 255u, b3 = m >> 24;
      colA[min(b0, 18u) << 6] += (b0 < K_CLS) ? 1.f : 0.f;
      colA[min(b1, 18u) << 6] += (b1 < K_CLS) ? 1.f : 0.f;
      colA[min(b2, 18u) << 6] += (b2 < K_CLS) ? 1.f : 0.f;
      colA[min(b3, 18u) << 6] += (b3 < K_CLS) ? 1.f : 0.f;
    }

    float acc[K_CLS];
#pragma unroll
    for (int k = 0; k < K_CLS; ++k) acc[k] = colA[k << 6];
#pragma unroll
    for (int k = 0; k < K_CLS; ++k) {
      float s = acc[k];
#pragma unroll
      for (int m = 1; m < 64; m <<= 1) s += __shfl_xor(s, m, 64);
      acc[k] = s;
    }
#pragma unroll
    for (int k = 0; k < K_CLS; ++k)
      if (lane == k) s_w[w][k] = acc[k];
    __syncthreads();
    if (t < K_CLS) {
      const int slot = idx;
      ws[OFF_PCNT + slot * 20 + t] = s_w[0][t] + s_w[1][t] + s_w[2][t] + s_w[3][t];
    }
  }
}

// ---- Reduce: 627 one-wave blocks, lane = slot -----------------------------
__global__ __launch_bounds__(64) void k_reduce(float* __restrict__ ws)
{
  const int o = blockIdx.x;            // 0..626
  const int lane = threadIdx.x;        // 0..63 = slot
  float a;
  if (o < C_CH * K_CLS) {
    const int ch = o / K_CLS, k = o - ch * K_CLS;
    a = ws[OFF_PSUM + ch * (64 * 20) + lane * 20 + k];
  } else {
    a = ws[OFF_PCNT + lane * 20 + (o - C_CH * K_CLS)];
  }
#pragma unroll
  for (int m = 1; m < 64; m <<= 1) a += __shfl_xor(a, m, 64);
  if (lane == 0) ws[OFF_RED + o] = a;
}

// ---- Pass 2 v7: CHANNEL-OUTER contiguous reads + bpermute ctr gather ------
// Block = 2048 px; per channel c, one contiguous 8KB chunk. Thread owns 8 px
// (t*4..t*4+3 and 1024+t*4..+3). nrm/dot in regs; d2 = nrm - 2dot + c2.
__global__ __launch_bounds__(256) void k_var(
    const float* __restrict__ pred, const int* __restrict__ tgt,
    float* __restrict__ ws)
{
  __shared__ float s_red[640];
  __shared__ float s_w[4][40];
  const int t = threadIdx.x;
  const int w = t >> 6;
  const int lane = t & 63;

  for (int i = t; i < 627; i += 256) s_red[i] = ws[OFF_RED + i];
  __syncthreads();

  // lane k (k<19) holds ctr[c][k]; lanes >=19 hold 0
  const float invc = (lane < K_CLS) ? 1.f / fmaxf(s_red[608 + lane], 1.f) : 0.f;
  float ctrreg[C_CH];
  float c2reg = 0.f;
#pragma unroll
  for (int c = 0; c < C_CH; ++c) {
    ctrreg[c] = (lane < K_CLS) ? s_red[c * K_CLS + lane] * invc : 0.f;
    c2reg = fmaf(ctrreg[c], ctrreg[c], c2reg);
  }

  const int bpx = blockIdx.x * 2048;
  const int n_idx = bpx >> HW_SHIFT;
  const int hw0 = bpx & (HW_SIZE - 1);

  // classes for this thread's 8 px
  const int* tb = tgt + (((size_t)n_idx) << HW_SHIFT) + hw0;
  const int4 ca = *reinterpret_cast<const int4*>(tb + t * 4);
  const int4 cb = *reinterpret_cast<const int4*>(tb + 1024 + t * 4);
  const int cls[8] = {ca.x, ca.y, ca.z, ca.w, cb.x, cb.y, cb.z, cb.w};
  int idx8[8];
#pragma unroll
  for (int j = 0; j < 8; ++j)
    idx8[j] = min((unsigned)cls[j], 19u) << 2;   // invalid -> lane 19 (ctr=0)

  float nrm[8] = {0.f,0.f,0.f,0.f,0.f,0.f,0.f,0.f};
  float dot[8] = {0.f,0.f,0.f,0.f,0.f,0.f,0.f,0.f};
#pragma unroll
  for (int c = 0; c < C_CH; ++c) {
    const float* cp = pred + (((size_t)(n_idx * C_CH + c)) << HW_SHIFT) + hw0;
    const float4 xa = *reinterpret_cast<const float4*>(cp + t * 4);
    const float4 xb = *reinterpret_cast<const float4*>(cp + 1024 + t * 4);
    const float x[8] = {xa.x, xa.y, xa.z, xa.w, xb.x, xb.y, xb.z, xb.w};
#pragma unroll
    for (int j = 0; j < 8; ++j) {
      const float cv = bperm(ctrreg[c], idx8[j]);
      nrm[j] = fmaf(x[j], x[j], nrm[j]);
      dot[j] = fmaf(x[j], cv, dot[j]);
    }
  }

  float acc_sq[K_CLS], acc_pos[K_CLS];
#pragma unroll
  for (int k = 0; k < K_CLS; ++k) { acc_sq[k] = 0.f; acc_pos[k] = 0.f; }
#pragma unroll
  for (int j = 0; j < 8; ++j) {
    const float c2j = bperm(c2reg, idx8[j]);
    const float d2 = fmaxf(nrm[j] - 2.f * dot[j] + c2j, 0.f);
    const float r = sqrtf(d2 + EPSF) - THEA_F;
    const bool act = ((unsigned)cls[j] < K_CLS) && (r > 0.f);
    const float rr = act ? r * r : 0.f;
    const float pp = act ? 1.f : 0.f;
    const int sc = min((unsigned)cls[j], 18u);
#pragma unroll
    for (int k = 0; k < K_CLS; ++k) {
      const bool b = (sc == k);
      acc_sq[k]  += b ? rr : 0.f;
      acc_pos[k] += b ? pp : 0.f;
    }
  }

  // wave shfl reduce -> 4-wave combine -> vpart
#pragma unroll
  for (int k = 0; k < K_CLS; ++k) {
    float a = acc_sq[k], b = acc_pos[k];
#pragma unroll
    for (int m = 1; m < 64; m <<= 1) {
      a += __shfl_xor(a, m, 64);
      b += __shfl_xor(b, m, 64);
    }
    acc_sq[k] = a; acc_pos[k] = b;
  }
#pragma unroll
  for (int k = 0; k < K_CLS; ++k)
    if (lane == k) { s_w[w][k] = acc_sq[k]; s_w[w][20 + k] = acc_pos[k]; }
  __syncthreads();
  if (t < K_CLS) {
    float* vp = ws + OFF_VPART + (size_t)blockIdx.x * 64;
    vp[t]         = s_w[0][t] + s_w[1][t] + s_w[2][t] + s_w[3][t];
    vp[K_CLS + t] = s_w[0][20 + t] + s_w[1][20 + t] + s_w[2][20 + t] + s_w[3][20 + t];
  }
}

// ---- Pre-reduce sq/pos: 38 blocks over 1024 partials ----------------------
__global__ __launch_bounds__(256) void k_vred(float* __restrict__ ws)
{
  const int o = blockIdx.x;            // 0..37
  const int t = threadIdx.x;
  float a = 0.f;
#pragma unroll
  for (int r = 0; r < 4; ++r)
    a += ws[OFF_VPART + (size_t)(t + r * 256) * 64 + o];
#pragma unroll
  for (int m = 1; m < 64; m <<= 1) a += __shfl_xor(a, m, 64);
  __shared__ float s[4];
  if ((t & 63) == 0) s[t >> 6] = a;
  __syncthreads();
  if (t == 0) ws[OFF_VRED + o] = s[0] + s[1] + s[2] + s[3];
}

// ---- Finalize -------------------------------------------------------------
__global__ __launch_bounds__(1024) void k_final(
    float* __restrict__ ws, float* __restrict__ out)
{
  __shared__ float s_ctr[C_CH * K_CLS];
  __shared__ float s_valid[K_CLS];
  __shared__ float s_red[3];
  __shared__ float s_ncls;
  const int t = threadIdx.x;
  if (t < 3) s_red[t] = 0.f;
  if (t < K_CLS) s_valid[t] = (ws[OFF_RED + C_CH * K_CLS + t] > MIN_PIX) ? 1.f : 0.f;
  for (int i = t; i < C_CH * K_CLS; i += 1024) {
    const int k = i % K_CLS;
    s_ctr[i] = ws[OFF_RED + i] / fmaxf(ws[OFF_RED + C_CH * K_CLS + k], 1.f);
  }
  __syncthreads();

  if (t == 0) {
    float n = 0.f;
    for (int k = 0; k < K_CLS; ++k) n += s_valid[k];
    s_ncls = fmaxf(n, 1.f);
  }
  if (t < K_CLS && s_valid[t] > 0.f) {
    const float sq  = ws[OFF_VRED + t];
    const float pos = ws[OFF_VRED + K_CLS + t];
    atomAddF(&s_red[0], sq / fmaxf(pos, 1.f));
    float nn = 0.f;
#pragma unroll
    for (int ch = 0; ch < C_CH; ++ch) {
      const float cv = s_ctr[ch * K_CLS + t];
      nn = fmaf(cv, cv, nn);
    }
    atomAddF(&s_red[2], sqrtf(nn + EPSF));
  }
  if (t < K_CLS * K_CLS) {
    const int a = t / K_CLS, b = t - (t / K_CLS) * K_CLS;
    if (a != b && s_valid[a] > 0.f && s_valid[b] > 0.f) {
      float dd = 0.f;
#pragma unroll
      for (int ch = 0; ch < C_CH; ++ch) {
        const float df = s_ctr[ch * K_CLS + a] - s_ctr[ch * K_CLS + b];
        dd = fmaf(df, df, dd);
      }
      const float dist = sqrtf(dd + EPSF);
      const float d = fmaxf(TWO_DELTA - dist, 0.f);
      if (d > 0.f) atomAddF(&s_red[1], d * d);
    }
  }
  __syncthreads();
  if (t == 0) {
    const float n = s_ncls;
    out[0] = s_red[0] / n
           + s_red[1] / fmaxf(n * (n - 1.f), 1.f)
           + 0.001f * s_red[2] / n;
  }
}

extern "C" void kernel_launch(void* const* d_in, const int* in_sizes, int n_in,
                              void* d_out, int out_size, void* d_ws, size_t ws_size,
                              hipStream_t stream) {
  const float* pred = (const float*)d_in[0];
  const int*   tgt  = (const int*)d_in[1];
  float* ws  = (float*)d_ws;
  float* out = (float*)d_out;
  const int P = in_sizes[1];            // n*h*w = 2097152

  k_pack  <<<P / 1024, 256, 0, stream>>>(tgt, ws);         // 2MB u8 map
  k_accum <<<2048 + 64, 256, 0, stream>>>(pred, ws);       // 2048 sum + 64 count
  k_reduce<<<C_CH * K_CLS + K_CLS, 64, 0, stream>>>(ws);   // 627 one-wave blocks
  k_var   <<<P / 2048, 256, 0, stream>>>(pred, tgt, ws);   // 1024 blocks
  k_vred  <<<2 * K_CLS, 256, 0, stream>>>(ws);             // 38 blocks
  k_final <<<1, 1024, 0, stream>>>(ws, out);
}